// Round 5
// baseline (485.325 us; speedup 1.0000x reference)
//
#include <hip/hip_runtime.h>
#include <hip/hip_bf16.h>
#include <math.h>

#define B_  8
#define C_  512
#define N_  1024
#define NH_ 8
#define HD_ 64
#define C3_ 1536

// ---- R5 ATTRIBUTION ROUND: idempotent in-kernel repeat loops ----
// Each kernel re-executes its full body k times (pure function -> same result).
// Purpose: multiply per-dispatch durations above the 43.5us harness-fill floor
// so all four kernels surface in rocprof top-5. Real per-kernel time = shown/k.
#define RP_PREP 12
#define RP_QKV   4
#define RP_ATTN  6
#define RP_PROJ  8

typedef __bf16 bf16x8  __attribute__((ext_vector_type(8)));
typedef __bf16 bf16x4v __attribute__((ext_vector_type(4)));
typedef float  f32x4   __attribute__((ext_vector_type(4)));
typedef __hip_bfloat16 bf16;

__device__ __forceinline__ f32x4 mfma16(const bf16x8& a, const bf16x8& b, const f32x4& c) {
    return __builtin_amdgcn_mfma_f32_16x16x32_bf16(a, b, c, 0, 0, 0);
}

// async global->LDS, 16B per lane. LDS dest = wave-uniform base + lane*16.
__device__ __forceinline__ void ld_lds16(const bf16* g, bf16* l_uniform) {
    __builtin_amdgcn_global_load_lds(
        (const __attribute__((address_space(1))) void*)(uintptr_t)g,
        (__attribute__((address_space(3))) void*)(uintptr_t)l_uniform,
        16, 0, 0);
}

// ds_read_b64_tr_b16, crossbar semantics (verified R3): each lane reads 8
// CONTIGUOUS bytes at its own vaddr; a fixed crossbar within each 16-lane group
// gives out[lane l][elem j] = column (l&15) of the group's 4x16 row-major block.
// vaddr = base + (l>>4)*256 + ((l&15)>>2)*32 + ((l&15)&3)*8; offset:N shifts block.
#define TRRD(d, a)    asm volatile("ds_read_b64_tr_b16 %0, %1"            : "=v"(d) : "v"(a))
#define TRRD128(d, a) asm volatile("ds_read_b64_tr_b16 %0, %1 offset:128" : "=v"(d) : "v"(a))

// ---------------- prep: x transpose + weight conversion, one launch ----------------
__global__ __launch_bounds__(256) void prep(const float* __restrict__ x,
                                            const float* __restrict__ Wq,
                                            const float* __restrict__ Wp,
                                            bf16* __restrict__ xb,
                                            bf16* __restrict__ Wqb,
                                            bf16* __restrict__ Wpb) {
    const int tid = threadIdx.x;
    __shared__ float T[32][33];
    for (int rep = 0; rep < RP_PREP; ++rep) {
        asm volatile("" ::: "memory");
        __syncthreads();                         // T reuse across reps
        if (blockIdx.x < 4096) {
            int t = blockIdx.x;
            const int n0 = (t & 31) * 32; t >>= 5;
            const int c0 = (t & 15) * 32; t >>= 4;
            const int b  = t;
            const int tx = tid & 31, ty = tid >> 5;
            const float* xp = x + ((size_t)b * C_ + c0) * N_ + n0;
#pragma unroll
            for (int l = 0; l < 4; ++l)
                T[ty + 8 * l][tx] = xp[(ty + 8 * l) * N_ + tx];
            __syncthreads();
            bf16* xo = xb + ((size_t)b * N_ + n0) * C_ + c0;
#pragma unroll
            for (int l = 0; l < 4; ++l)
                xo[(ty + 8 * l) * C_ + tx] = __float2bfloat16(T[tx][ty + 8 * l]);
        } else {
            const int base = (blockIdx.x - 4096) * 1024 + tid * 4;   // 4 elems/thread
            const float* src;
            bf16* dst;
            int off;
            if (base < C3_ * C_) { src = Wq; dst = Wqb; off = base; }
            else                 { src = Wp; dst = Wpb; off = base - C3_ * C_; }
            f32x4 w = *(const f32x4*)(src + off);
            bf16x4v o;
#pragma unroll
            for (int i = 0; i < 4; ++i) o[i] = (__bf16)w[i];
            *(bf16x4v*)(dst + off) = o;
        }
    }
}

// ---------------- QKV GEMM: 8192x1536x512, 128x128 tiles, ping-pong dbuf ----------------
__global__ __launch_bounds__(256) void qkv_mfma(const bf16* __restrict__ xb,
                                                const bf16* __restrict__ Wqb,
                                                const float* __restrict__ bq,
                                                bf16* __restrict__ Qb,
                                                bf16* __restrict__ Kb,
                                                bf16* __restrict__ Vt) {
    __shared__ bf16 As[2][128 * 32];
    __shared__ bf16 Bs[2][128 * 32];
    __shared__ bf16 Vl[4][16][20];
    const int tid = threadIdx.x, w = tid >> 6, lane = tid & 63;
    const int lo = lane & 15, hi = lane >> 4;
    const int j0 = blockIdx.x * 128;
    const int m0 = blockIdx.y * 128;
    const int b  = m0 >> 10;

    const int srow = w * 32 + (lane >> 2);
    const int scol = (lane & 3) * 8;
    const bf16* gA = xb  + (size_t)(m0 + srow) * C_ + scol;
    const bf16* gB = Wqb + (size_t)(j0 + srow) * C_ + scol;
    const int lws = (w * 32) * 32;               // wave-uniform LDS write offset

    for (int rep = 0; rep < RP_QKV; ++rep) {
        asm volatile("" ::: "memory");
        __syncthreads();                         // buffer reuse across reps

        f32x4 acc[4][4];
#pragma unroll
        for (int mt = 0; mt < 4; ++mt)
#pragma unroll
            for (int jt = 0; jt < 4; ++jt)
                acc[mt][jt] = (f32x4){0.f, 0.f, 0.f, 0.f};

        auto STAGE = [&](bf16* Ab, bf16* Bb, int k0) {
            ld_lds16(gA + k0, Ab + lws);
            ld_lds16(gA + (size_t)16 * C_ + k0, Ab + lws + 16 * 32);
            ld_lds16(gB + k0, Bb + lws);
            ld_lds16(gB + (size_t)16 * C_ + k0, Bb + lws + 16 * 32);
        };
        auto COMPUTE = [&](const bf16* Ab, const bf16* Bb) {
            bf16x8 af[4], bfr[4];
#pragma unroll
            for (int mt = 0; mt < 4; ++mt)
                af[mt] = *(const bf16x8*)(Ab + ((w & 1) * 64 + mt * 16 + lo) * 32 + hi * 8);
#pragma unroll
            for (int jt = 0; jt < 4; ++jt)
                bfr[jt] = *(const bf16x8*)(Bb + ((w >> 1) * 64 + jt * 16 + lo) * 32 + hi * 8);
#pragma unroll
            for (int mt = 0; mt < 4; ++mt)
#pragma unroll
                for (int jt = 0; jt < 4; ++jt)
                    acc[mt][jt] = mfma16(af[mt], bfr[jt], acc[mt][jt]);
        };

        STAGE(As[0], Bs[0], 0);                  // prologue: k0=0 into buf 0
#pragma unroll
        for (int k0 = 0; k0 < C_; k0 += 64) {
            __syncthreads();
            if (k0 + 32 < C_) STAGE(As[1], Bs[1], k0 + 32);
            COMPUTE(As[0], Bs[0]);
            __syncthreads();
            if (k0 + 64 < C_) STAGE(As[0], Bs[0], k0 + 64);
            COMPUTE(As[1], Bs[1]);
        }

        const int jb = (w >> 1) * 64;
        const int nbase = (m0 & 1023) + (w & 1) * 64;
#pragma unroll
        for (int jt = 0; jt < 4; ++jt) {
            const int j16 = j0 + jb + jt * 16;
            const float bias = bq[j16 + lo];
            if (j16 < 512) {
                const int h = j16 >> 6, d = (j16 & 63) + lo;
                bf16* qp = Qb + ((size_t)(b * NH_ + h) * N_) * HD_ + d;
#pragma unroll
                for (int mt = 0; mt < 4; ++mt)
#pragma unroll
                    for (int r = 0; r < 4; ++r) {
                        int n = nbase + mt * 16 + hi * 4 + r;
                        // 0.125 * log2(e): attn uses exp2, so fold log2(e) into Q's scale
                        qp[(size_t)n * HD_] = __float2bfloat16((acc[mt][jt][r] + bias) * 0.18033688f);
                    }
            } else if (j16 < 1024) {
                const int jj = j16 - 512;
                const int h = jj >> 6, d = (jj & 63) + lo;
                bf16* kp = Kb + ((size_t)(b * NH_ + h) * N_) * HD_ + d;
#pragma unroll
                for (int mt = 0; mt < 4; ++mt)
#pragma unroll
                    for (int r = 0; r < 4; ++r) {
                        int n = nbase + mt * 16 + hi * 4 + r;
                        kp[(size_t)n * HD_] = __float2bfloat16(acc[mt][jt][r] + bias);
                    }
            } else {
                const int jj = j16 - 1024;
                const int h = jj >> 6, dbase = jj & 63;
                bf16* vp = Vt + ((size_t)(b * NH_ + h) * HD_ + dbase) * N_ + nbase;
#pragma unroll
                for (int mt = 0; mt < 4; ++mt) {
#pragma unroll
                    for (int r = 0; r < 4; ++r)
                        Vl[w][hi * 4 + r][lo] = __float2bfloat16(acc[mt][jt][r] + bias);
#pragma unroll
                    for (int r = 0; r < 4; ++r)
                        vp[(size_t)(hi * 4 + r) * N_ + mt * 16 + lo] = Vl[w][lo][hi * 4 + r];
                }
            }
        }
    }
}

// ---------------- MFMA flash attention (R3-verified structure) ----------------
__global__ __launch_bounds__(256) void attn_mfma(const bf16* __restrict__ Qb,
                                                 const bf16* __restrict__ Kb,
                                                 const bf16* __restrict__ Vt,
                                                 bf16* __restrict__ ao) {
    __shared__ bf16 Ks0[2][64 * 32], Ks1[2][64 * 32];   // [buf][key][d-half]
    __shared__ bf16 Vs0[2][64 * 32], Vs1[2][64 * 32];   // [buf][d][key-half]
    __shared__ __align__(16) bf16 PT[4][2][64][16];     // [wave][qgrp][key][q] = P^T

    const int tid  = threadIdx.x;
    const int wv   = tid >> 6;
    const int lane = tid & 63;
    const int lo   = lane & 15;
    const int hi   = lane >> 4;
    const int bh   = blockIdx.x & 63;            // XCD = bh & 7
    const int blk  = blockIdx.x >> 6;            // 0..7
    const int pi   = blk * 4 + wv;               // 0..31
    const int qwA  = pi * 16;
    const int qwB  = (63 - pi) * 16;

    const bf16* Qh = Qb + (size_t)bh * N_ * HD_;
    const bf16* Kh = Kb + (size_t)bh * N_ * HD_;
    const bf16* Vh = Vt + (size_t)bh * HD_ * N_;

    const int srow = tid >> 2;
    const int scol = (tid & 3) * 8;
    const bf16* gK = Kh + (size_t)srow * HD_ + scol;
    const bf16* gV = Vh + (size_t)srow * N_ + scol;
    const int lofs = wv * 512;                   // wave-uniform LDS offset

    const unsigned ptA = (unsigned)(uintptr_t)&PT[wv][0][0][0]
                         + hi * 256 + (lo >> 2) * 32 + (lo & 3) * 8;
    const unsigned ptB = ptA + 2048;

    const int nkbA   = (qwA + 79) >> 6;
    const int nkbB   = (qwB + 79) >> 6;
    const int nkbBlk = ((63 - blk * 4) * 16 + 79) >> 6;

    for (int rep = 0; rep < RP_ATTN; ++rep) {
        asm volatile("" ::: "memory");
        __syncthreads();                         // LDS buffer reuse across reps

        const bf16x8 qA0 = *(const bf16x8*)(Qh + (qwA + lo) * HD_ + hi * 8);
        const bf16x8 qA1 = *(const bf16x8*)(Qh + (qwA + lo) * HD_ + 32 + hi * 8);
        const bf16x8 qB0 = *(const bf16x8*)(Qh + (qwB + lo) * HD_ + hi * 8);
        const bf16x8 qB1 = *(const bf16x8*)(Qh + (qwB + lo) * HD_ + 32 + hi * 8);

        f32x4 OA[4], OB[4];
        float LA[4], LB[4];
#pragma unroll
        for (int r = 0; r < 4; ++r) {
            OA[0][r] = OA[1][r] = OA[2][r] = OA[3][r] = 0.f;
            OB[0][r] = OB[1][r] = OB[2][r] = OB[3][r] = 0.f;
            LA[r] = 0.f; LB[r] = 0.f;
        }

        {
            ld_lds16(gK,      Ks0[0] + lofs);
            ld_lds16(gK + 32, Ks1[0] + lofs);
            ld_lds16(gV,      Vs0[0] + lofs);
            ld_lds16(gV + 32, Vs1[0] + lofs);
        }

        for (int kb = 0; kb < nkbBlk; ++kb) {
            const int key0 = kb * 64;
            const int cur  = kb & 1;

            __syncthreads();                     // drains cur's staging

            if (kb + 1 < nkbBlk) {               // prefetch kb+1 into the other buffer
                const size_t nk = (size_t)(key0 + 64);
                ld_lds16(gK + nk * HD_,      Ks0[cur ^ 1] + lofs);
                ld_lds16(gK + nk * HD_ + 32, Ks1[cur ^ 1] + lofs);
                ld_lds16(gV + nk,            Vs0[cur ^ 1] + lofs);
                ld_lds16(gV + nk + 32,       Vs1[cur ^ 1] + lofs);
            }

            if (kb < nkbB) {
                const bool doA = (kb < nkbA);

                bf16x8 kf[4][2], vf[4][2];
#pragma unroll
                for (int t = 0; t < 4; ++t) {
                    kf[t][0] = *(const bf16x8*)(Ks0[cur] + (t * 16 + lo) * 32 + hi * 8);
                    kf[t][1] = *(const bf16x8*)(Ks1[cur] + (t * 16 + lo) * 32 + hi * 8);
                    vf[t][0] = *(const bf16x8*)(Vs0[cur] + (t * 16 + lo) * 32 + hi * 8);
                    vf[t][1] = *(const bf16x8*)(Vs1[cur] + (t * 16 + lo) * 32 + hi * 8);
                }

                f32x4 SB[4], SA[4];
#pragma unroll
                for (int t = 0; t < 4; ++t) {
                    SB[t] = (f32x4){0.f, 0.f, 0.f, 0.f};
                    SB[t] = mfma16(qB0, kf[t][0], SB[t]);
                    SB[t] = mfma16(qB1, kf[t][1], SB[t]);
                }
                if (doA) {
#pragma unroll
                    for (int t = 0; t < 4; ++t) {
                        SA[t] = (f32x4){0.f, 0.f, 0.f, 0.f};
                        SA[t] = mfma16(qA0, kf[t][0], SA[t]);
                        SA[t] = mfma16(qA1, kf[t][1], SA[t]);
                    }
                }

                if (key0 + 63 > qwB) {
#pragma unroll
                    for (int t = 0; t < 4; ++t)
#pragma unroll
                        for (int r = 0; r < 4; ++r)
                            if (key0 + t * 16 + lo > qwB + hi * 4 + r) SB[t][r] = -1e30f;
                }
                if (doA && key0 + 63 > qwA) {
#pragma unroll
                    for (int t = 0; t < 4; ++t)
#pragma unroll
                        for (int r = 0; r < 4; ++r)
                            if (key0 + t * 16 + lo > qwA + hi * 4 + r) SA[t][r] = -1e30f;
                }

                bf16x4v pk;
#pragma unroll
                for (int t = 0; t < 4; ++t) {
#pragma unroll
                    for (int r = 0; r < 4; ++r) {
                        float p = exp2f(SB[t][r]);
                        LB[r] += p;
                        pk[r] = (__bf16)p;
                    }
                    *(bf16x4v*)&PT[wv][1][t * 16 + lo][hi * 4] = pk;   // ds_write_b64
                }
                if (doA) {
#pragma unroll
                    for (int t = 0; t < 4; ++t) {
#pragma unroll
                        for (int r = 0; r < 4; ++r) {
                            float p = exp2f(SA[t][r]);
                            LA[r] += p;
                            pk[r] = (__bf16)p;
                        }
                        *(bf16x4v*)&PT[wv][0][t * 16 + lo][hi * 4] = pk;
                    }
                }
                asm volatile("s_waitcnt lgkmcnt(0)" ::: "memory");   // P^T stores visible

                bf16x4v b00, b01, b10, b11, a00, a01, a10, a11;
                TRRD(b00, ptB);          TRRD128(b01, ptB);
                TRRD(b10, ptB + 1024);   TRRD128(b11, ptB + 1024);
                if (doA) {
                    TRRD(a00, ptA);        TRRD128(a01, ptA);
                    TRRD(a10, ptA + 1024); TRRD128(a11, ptA + 1024);
                }
                asm volatile("s_waitcnt lgkmcnt(0)" ::: "memory");
                __builtin_amdgcn_sched_barrier(0);                   // rule #18

                const bf16x8 paB0 = __builtin_shufflevector(b00, b01, 0, 1, 2, 3, 4, 5, 6, 7);
                const bf16x8 paB1 = __builtin_shufflevector(b10, b11, 0, 1, 2, 3, 4, 5, 6, 7);
#pragma unroll
                for (int t = 0; t < 4; ++t) {
                    OB[t] = mfma16(paB0, vf[t][0], OB[t]);
                    OB[t] = mfma16(paB1, vf[t][1], OB[t]);
                }
                if (doA) {
                    const bf16x8 paA0 = __builtin_shufflevector(a00, a01, 0, 1, 2, 3, 4, 5, 6, 7);
                    const bf16x8 paA1 = __builtin_shufflevector(a10, a11, 0, 1, 2, 3, 4, 5, 6, 7);
#pragma unroll
                    for (int t = 0; t < 4; ++t) {
                        OA[t] = mfma16(paA0, vf[t][0], OA[t]);
                        OA[t] = mfma16(paA1, vf[t][1], OA[t]);
                    }
                }
            }
        }

        const int b = bh >> 3, h = bh & 7;
#pragma unroll
        for (int c = 0; c < 2; ++c) {
            const int qw = c ? qwB : qwA;
            f32x4* O = c ? OB : OA;
            float* Lp = c ? LB : LA;
            float rL[4];
#pragma unroll
            for (int r = 0; r < 4; ++r) {
                float Ls = Lp[r];
#pragma unroll
                for (int off = 1; off < 16; off <<= 1)
                    Ls += __shfl_xor(Ls, off, 64);
                rL[r] = 1.f / Ls;
            }
#pragma unroll
            for (int t = 0; t < 4; ++t)
#pragma unroll
                for (int r = 0; r < 4; ++r) {
                    int q = qw + hi * 4 + r;
                    ao[((size_t)b * N_ + q) * C_ + h * HD_ + t * 16 + lo] =
                        __float2bfloat16(O[t][r] * rL[r]);
                }
        }
    }
}

// ---------------- Projection GEMM: 512x8192x512, 64j x 128n tiles, ping-pong dbuf ----------------
__global__ __launch_bounds__(256) void proj_mfma(const bf16* __restrict__ aob,
                                                 const bf16* __restrict__ Wpb,
                                                 const float* __restrict__ bp,
                                                 float* __restrict__ out) {
    __shared__ bf16 As[2][64 * 32];
    __shared__ bf16 Bs[2][128 * 32];
    const int tid = threadIdx.x, w = tid >> 6, lane = tid & 63;
    const int lo = lane & 15, hi = lane >> 4;
    const int j0 = blockIdx.x * 64;
    const int n0 = blockIdx.y * 128;
    const int b  = n0 >> 10;

    const int r4 = lane >> 2, c8 = (lane & 3) * 8;
    const bf16* gA = Wpb + (size_t)(j0 + w * 16 + r4) * C_ + c8;
    const bf16* gB = aob + (size_t)(n0 + w * 32 + r4) * C_ + c8;
    const int lwsA = (w * 16) * 32;
    const int lwsB = (w * 32) * 32;

    for (int rep = 0; rep < RP_PROJ; ++rep) {
        asm volatile("" ::: "memory");
        __syncthreads();                         // buffer reuse across reps

        f32x4 acc[2][4];
#pragma unroll
        for (int mt = 0; mt < 2; ++mt)
#pragma unroll
            for (int jt = 0; jt < 4; ++jt)
                acc[mt][jt] = (f32x4){0.f, 0.f, 0.f, 0.f};

        auto STAGE = [&](bf16* Ab, bf16* Bb, int k0) {
            ld_lds16(gA + k0, Ab + lwsA);
            ld_lds16(gB + k0, Bb + lwsB);
            ld_lds16(gB + (size_t)16 * C_ + k0, Bb + lwsB + 16 * 32);
        };
        auto COMPUTE = [&](const bf16* Ab, const bf16* Bb) {
            bf16x8 af[2], bfr[4];
#pragma unroll
            for (int mt = 0; mt < 2; ++mt)
                af[mt] = *(const bf16x8*)(Ab + ((w & 1) * 32 + mt * 16 + lo) * 32 + hi * 8);
#pragma unroll
            for (int jt = 0; jt < 4; ++jt)
                bfr[jt] = *(const bf16x8*)(Bb + ((w >> 1) * 64 + jt * 16 + lo) * 32 + hi * 8);
#pragma unroll
            for (int mt = 0; mt < 2; ++mt)
#pragma unroll
                for (int jt = 0; jt < 4; ++jt)
                    acc[mt][jt] = mfma16(af[mt], bfr[jt], acc[mt][jt]);
        };

        STAGE(As[0], Bs[0], 0);
#pragma unroll
        for (int k0 = 0; k0 < C_; k0 += 64) {
            __syncthreads();
            if (k0 + 32 < C_) STAGE(As[1], Bs[1], k0 + 32);
            COMPUTE(As[0], Bs[0]);
            __syncthreads();
            if (k0 + 64 < C_) STAGE(As[0], Bs[0], k0 + 64);
            COMPUTE(As[1], Bs[1]);
        }

#pragma unroll
        for (int mt = 0; mt < 2; ++mt)
#pragma unroll
            for (int r = 0; r < 4; ++r) {
                const int j = j0 + (w & 1) * 32 + mt * 16 + hi * 4 + r;
                const float bias = bp[j];
                float* op = out + ((size_t)(b * C_ + j)) * N_ + (n0 & 1023) + (w >> 1) * 64 + lo;
#pragma unroll
                for (int jt = 0; jt < 4; ++jt)
                    op[jt * 16] = acc[mt][jt][r] + bias;
            }
    }
}

extern "C" void kernel_launch(void* const* d_in, const int* in_sizes, int n_in,
                              void* d_out, int out_size, void* d_ws, size_t ws_size,
                              hipStream_t stream) {
    const float* x  = (const float*)d_in[0];
    const float* Wq = (const float*)d_in[1];
    const float* bq = (const float*)d_in[2];
    const float* Wp = (const float*)d_in[3];
    const float* bp = (const float*)d_in[4];
    float* out = (float*)d_out;

    const size_t headElems = (size_t)B_ * NH_ * N_ * HD_;
    bf16* xb  = (bf16*)d_ws;
    bf16* Wqb = xb + (size_t)B_ * N_ * C_;
    bf16* Wpb = Wqb + (size_t)C3_ * C_;
    bf16* Qb  = Wpb + (size_t)C_ * C_;
    bf16* Kb  = Qb + headElems;
    bf16* Vt  = Kb + headElems;
    bf16* aob = Vt + headElems;

    prep<<<dim3(4096 + 1024), dim3(256), 0, stream>>>(x, Wq, Wp, xb, Wqb, Wpb);

    qkv_mfma<<<dim3(C3_ / 128, (B_ * N_) / 128), dim3(256), 0, stream>>>(xb, Wqb, bq, Qb, Kb, Vt);
    attn_mfma<<<dim3(8 * 64), dim3(256), 0, stream>>>(Qb, Kb, Vt, aob);
    proj_mfma<<<dim3(C_ / 64, (B_ * N_) / 128), dim3(256), 0, stream>>>(aob, Wpb, bp, out);
}

// Round 6
// 139.396 us; speedup vs baseline: 3.4816x; 3.4816x over previous
//
#include <hip/hip_runtime.h>
#include <hip/hip_bf16.h>
#include <math.h>

#define B_  8
#define C_  512
#define N_  1024
#define NH_ 8
#define HD_ 64
#define C3_ 1536

typedef __bf16 bf16x8  __attribute__((ext_vector_type(8)));
typedef __bf16 bf16x4v __attribute__((ext_vector_type(4)));
typedef float  f32x4   __attribute__((ext_vector_type(4)));
typedef __hip_bfloat16 bf16;

__device__ __forceinline__ f32x4 mfma16(const bf16x8& a, const bf16x8& b, const f32x4& c) {
    return __builtin_amdgcn_mfma_f32_16x16x32_bf16(a, b, c, 0, 0, 0);
}

// async global->LDS, 16B per lane. LDS dest = wave-uniform base + lane*16.
__device__ __forceinline__ void ld_lds16(const bf16* g, bf16* l_uniform) {
    __builtin_amdgcn_global_load_lds(
        (const __attribute__((address_space(1))) void*)(uintptr_t)g,
        (__attribute__((address_space(3))) void*)(uintptr_t)l_uniform,
        16, 0, 0);
}

// ds_read_b64_tr_b16, crossbar semantics (verified R3): each lane reads 8
// CONTIGUOUS bytes at its own vaddr; a fixed crossbar within each 16-lane group
// gives out[lane l][elem j] = column (l&15) of the group's 4x16 row-major block.
// vaddr = base + (l>>4)*256 + ((l&15)>>2)*32 + ((l&15)&3)*8; offset:N shifts block.
#define TRRD(d, a)    asm volatile("ds_read_b64_tr_b16 %0, %1"            : "=v"(d) : "v"(a))
#define TRRD128(d, a) asm volatile("ds_read_b64_tr_b16 %0, %1 offset:128" : "=v"(d) : "v"(a))

// ---- R6: LDS bank-conflict swizzle (T2-analog) for [rows][32-elem] tiles ----
// Measured (R5 attribution): attn SQ_LDS_BANK_CONFLICT = 3.6e6/run; fragment
// reads ds_read_b128 at row*64B + hi*16B have bank period 2 in row -> 8-way.
// Fix (rule #21, both-sides): LDS dest stays LINEAR (global_load_lds), the
// GLOBAL source 16B-chunk is pre-swizzled c ^= s(row), and reads use hi^s(row),
// where s(row) = (row&3) ^ ((row>>2)&3). Residues mod 8 -> 2-way (free, m136).
// s is invariant under row+16 (staging's second call) and collapses to per-lane
// constants: staging ss = ((srow&3)^((srow>>2)&3)); read sl = (lane&3)^((lane>>2)&3)
// (read rows are w-const*16 + t*16 + lo, and 16|offsets keep s = s(lo)).

// ---------------- prep: x transpose + weight conversion, one launch ----------------
__global__ __launch_bounds__(256) void prep(const float* __restrict__ x,
                                            const float* __restrict__ Wq,
                                            const float* __restrict__ Wp,
                                            bf16* __restrict__ xb,
                                            bf16* __restrict__ Wqb,
                                            bf16* __restrict__ Wpb) {
    const int tid = threadIdx.x;
    if (blockIdx.x < 4096) {
        __shared__ float T[32][33];
        int t = blockIdx.x;
        const int n0 = (t & 31) * 32; t >>= 5;
        const int c0 = (t & 15) * 32; t >>= 4;
        const int b  = t;
        const int tx = tid & 31, ty = tid >> 5;
        const float* xp = x + ((size_t)b * C_ + c0) * N_ + n0;
#pragma unroll
        for (int l = 0; l < 4; ++l)
            T[ty + 8 * l][tx] = xp[(ty + 8 * l) * N_ + tx];
        __syncthreads();
        bf16* xo = xb + ((size_t)b * N_ + n0) * C_ + c0;
#pragma unroll
        for (int l = 0; l < 4; ++l)
            xo[(ty + 8 * l) * C_ + tx] = __float2bfloat16(T[tx][ty + 8 * l]);
    } else {
        const int base = (blockIdx.x - 4096) * 1024 + tid * 4;   // 4 elems/thread
        const float* src;
        bf16* dst;
        int off;
        if (base < C3_ * C_) { src = Wq; dst = Wqb; off = base; }
        else                 { src = Wp; dst = Wpb; off = base - C3_ * C_; }
        f32x4 w = *(const f32x4*)(src + off);
        bf16x4v o;
#pragma unroll
        for (int i = 0; i < 4; ++i) o[i] = (__bf16)w[i];
        *(bf16x4v*)(dst + off) = o;
    }
}

// ---------------- QKV GEMM: 8192x1536x512, 128x128 tiles, ping-pong dbuf ----------------
__global__ __launch_bounds__(256) void qkv_mfma(const bf16* __restrict__ xb,
                                                const bf16* __restrict__ Wqb,
                                                const float* __restrict__ bq,
                                                bf16* __restrict__ Qb,
                                                bf16* __restrict__ Kb,
                                                bf16* __restrict__ Vt) {
    __shared__ bf16 As[2][128 * 32];
    __shared__ bf16 Bs[2][128 * 32];
    __shared__ bf16 Vl[4][16][20];
    const int tid = threadIdx.x, w = tid >> 6, lane = tid & 63;
    const int lo = lane & 15, hi = lane >> 4;
    const int j0 = blockIdx.x * 128;
    const int m0 = blockIdx.y * 128;
    const int b  = m0 >> 10;

    const int srow = w * 32 + (lane >> 2);
    const int ss   = (srow & 3) ^ ((srow >> 2) & 3);         // staging swizzle (row+16 invariant)
    const int scol = (((lane & 3) ^ ss)) * 8;                // pre-swizzled global chunk
    const int sl   = (lane & 3) ^ ((lane >> 2) & 3);         // read swizzle s(lo)
    const bf16* gA = xb  + (size_t)(m0 + srow) * C_ + scol;
    const bf16* gB = Wqb + (size_t)(j0 + srow) * C_ + scol;
    const int lws = (w * 32) * 32;               // wave-uniform LDS write offset

    f32x4 acc[4][4];
#pragma unroll
    for (int mt = 0; mt < 4; ++mt)
#pragma unroll
        for (int jt = 0; jt < 4; ++jt)
            acc[mt][jt] = (f32x4){0.f, 0.f, 0.f, 0.f};

    auto STAGE = [&](bf16* Ab, bf16* Bb, int k0) {
        ld_lds16(gA + k0, Ab + lws);
        ld_lds16(gA + (size_t)16 * C_ + k0, Ab + lws + 16 * 32);
        ld_lds16(gB + k0, Bb + lws);
        ld_lds16(gB + (size_t)16 * C_ + k0, Bb + lws + 16 * 32);
    };
    auto COMPUTE = [&](const bf16* Ab, const bf16* Bb) {
        bf16x8 af[4], bfr[4];
#pragma unroll
        for (int mt = 0; mt < 4; ++mt)
            af[mt] = *(const bf16x8*)(Ab + ((w & 1) * 64 + mt * 16 + lo) * 32 + (hi ^ sl) * 8);
#pragma unroll
        for (int jt = 0; jt < 4; ++jt)
            bfr[jt] = *(const bf16x8*)(Bb + ((w >> 1) * 64 + jt * 16 + lo) * 32 + (hi ^ sl) * 8);
#pragma unroll
        for (int mt = 0; mt < 4; ++mt)
#pragma unroll
            for (int jt = 0; jt < 4; ++jt)
                acc[mt][jt] = mfma16(af[mt], bfr[jt], acc[mt][jt]);
    };

    STAGE(As[0], Bs[0], 0);                      // prologue: k0=0 into buf 0
#pragma unroll
    for (int k0 = 0; k0 < C_; k0 += 64) {
        __syncthreads();
        if (k0 + 32 < C_) STAGE(As[1], Bs[1], k0 + 32);
        COMPUTE(As[0], Bs[0]);
        __syncthreads();
        if (k0 + 64 < C_) STAGE(As[0], Bs[0], k0 + 64);
        COMPUTE(As[1], Bs[1]);
    }

    const int jb = (w >> 1) * 64;
    const int nbase = (m0 & 1023) + (w & 1) * 64;
#pragma unroll
    for (int jt = 0; jt < 4; ++jt) {
        const int j16 = j0 + jb + jt * 16;
        const float bias = bq[j16 + lo];
        if (j16 < 512) {
            const int h = j16 >> 6, d = (j16 & 63) + lo;
            bf16* qp = Qb + ((size_t)(b * NH_ + h) * N_) * HD_ + d;
#pragma unroll
            for (int mt = 0; mt < 4; ++mt)
#pragma unroll
                for (int r = 0; r < 4; ++r) {
                    int n = nbase + mt * 16 + hi * 4 + r;
                    // 0.125 * log2(e): attn uses exp2, so fold log2(e) into Q's scale
                    qp[(size_t)n * HD_] = __float2bfloat16((acc[mt][jt][r] + bias) * 0.18033688f);
                }
        } else if (j16 < 1024) {
            const int jj = j16 - 512;
            const int h = jj >> 6, d = (jj & 63) + lo;
            bf16* kp = Kb + ((size_t)(b * NH_ + h) * N_) * HD_ + d;
#pragma unroll
            for (int mt = 0; mt < 4; ++mt)
#pragma unroll
                for (int r = 0; r < 4; ++r) {
                    int n = nbase + mt * 16 + hi * 4 + r;
                    kp[(size_t)n * HD_] = __float2bfloat16(acc[mt][jt][r] + bias);
                }
        } else {
            const int jj = j16 - 1024;
            const int h = jj >> 6, dbase = jj & 63;
            bf16* vp = Vt + ((size_t)(b * NH_ + h) * HD_ + dbase) * N_ + nbase;
#pragma unroll
            for (int mt = 0; mt < 4; ++mt) {
#pragma unroll
                for (int r = 0; r < 4; ++r)
                    Vl[w][hi * 4 + r][lo] = __float2bfloat16(acc[mt][jt][r] + bias);
#pragma unroll
                for (int r = 0; r < 4; ++r)
                    vp[(size_t)(hi * 4 + r) * N_ + mt * 16 + lo] = Vl[w][lo][hi * 4 + r];
            }
        }
    }
}

// ---------------- MFMA flash attention (R3-verified structure + R6 K/V swizzle) ----------------
__global__ __launch_bounds__(256) void attn_mfma(const bf16* __restrict__ Qb,
                                                 const bf16* __restrict__ Kb,
                                                 const bf16* __restrict__ Vt,
                                                 bf16* __restrict__ ao) {
    __shared__ bf16 Ks0[2][64 * 32], Ks1[2][64 * 32];   // [buf][key][d-half]
    __shared__ bf16 Vs0[2][64 * 32], Vs1[2][64 * 32];   // [buf][d][key-half]
    __shared__ __align__(16) bf16 PT[4][2][64][16];     // [wave][qgrp][key][q] = P^T

    const int tid  = threadIdx.x;
    const int wv   = tid >> 6;
    const int lane = tid & 63;
    const int lo   = lane & 15;
    const int hi   = lane >> 4;
    const int bh   = blockIdx.x & 63;            // XCD = bh & 7
    const int blk  = blockIdx.x >> 6;            // 0..7
    const int pi   = blk * 4 + wv;               // 0..31
    const int qwA  = pi * 16;
    const int qwB  = (63 - pi) * 16;

    const bf16* Qh = Qb + (size_t)bh * N_ * HD_;
    const bf16* Kh = Kb + (size_t)bh * N_ * HD_;
    const bf16* Vh = Vt + (size_t)bh * HD_ * N_;

    const bf16x8 qA0 = *(const bf16x8*)(Qh + (qwA + lo) * HD_ + hi * 8);
    const bf16x8 qA1 = *(const bf16x8*)(Qh + (qwA + lo) * HD_ + 32 + hi * 8);
    const bf16x8 qB0 = *(const bf16x8*)(Qh + (qwB + lo) * HD_ + hi * 8);
    const bf16x8 qB1 = *(const bf16x8*)(Qh + (qwB + lo) * HD_ + 32 + hi * 8);

    // staging: 256 threads x 16B per call = one 64x32 half-tile (linear LDS dest)
    const int srow = tid >> 2;
    const int ss   = (srow & 3) ^ ((srow >> 2) & 3);
    const int scol = ((tid & 3) ^ ss) * 8;               // pre-swizzled global chunk
    const int sl   = (lane & 3) ^ ((lane >> 2) & 3);     // read swizzle s(lo)
    const bf16* gK = Kh + (size_t)srow * HD_ + scol;
    const bf16* gV = Vh + (size_t)srow * N_ + scol;
    const int lofs = wv * 512;                   // wave-uniform LDS offset

    const unsigned ptA = (unsigned)(uintptr_t)&PT[wv][0][0][0]
                         + hi * 256 + (lo >> 2) * 32 + (lo & 3) * 8;
    const unsigned ptB = ptA + 2048;

    f32x4 OA[4], OB[4];
    float LA[4], LB[4];
#pragma unroll
    for (int r = 0; r < 4; ++r) {
        OA[0][r] = OA[1][r] = OA[2][r] = OA[3][r] = 0.f;
        OB[0][r] = OB[1][r] = OB[2][r] = OB[3][r] = 0.f;
        LA[r] = 0.f; LB[r] = 0.f;
    }

    const int nkbA   = (qwA + 79) >> 6;
    const int nkbB   = (qwB + 79) >> 6;
    const int nkbBlk = ((63 - blk * 4) * 16 + 79) >> 6;

    {
        ld_lds16(gK,      Ks0[0] + lofs);
        ld_lds16(gK + 32, Ks1[0] + lofs);
        ld_lds16(gV,      Vs0[0] + lofs);
        ld_lds16(gV + 32, Vs1[0] + lofs);
    }

    for (int kb = 0; kb < nkbBlk; ++kb) {
        const int key0 = kb * 64;
        const int cur  = kb & 1;

        __syncthreads();                         // drains cur's staging

        if (kb + 1 < nkbBlk) {                   // prefetch kb+1 into the other buffer
            const size_t nk = (size_t)(key0 + 64);
            ld_lds16(gK + nk * HD_,      Ks0[cur ^ 1] + lofs);
            ld_lds16(gK + nk * HD_ + 32, Ks1[cur ^ 1] + lofs);
            ld_lds16(gV + nk,            Vs0[cur ^ 1] + lofs);
            ld_lds16(gV + nk + 32,       Vs1[cur ^ 1] + lofs);
        }

        if (kb < nkbB) {
            const bool doA = (kb < nkbA);

            bf16x8 kf[4][2], vf[4][2];
#pragma unroll
            for (int t = 0; t < 4; ++t) {
                kf[t][0] = *(const bf16x8*)(Ks0[cur] + (t * 16 + lo) * 32 + (hi ^ sl) * 8);
                kf[t][1] = *(const bf16x8*)(Ks1[cur] + (t * 16 + lo) * 32 + (hi ^ sl) * 8);
                vf[t][0] = *(const bf16x8*)(Vs0[cur] + (t * 16 + lo) * 32 + (hi ^ sl) * 8);
                vf[t][1] = *(const bf16x8*)(Vs1[cur] + (t * 16 + lo) * 32 + (hi ^ sl) * 8);
            }

            f32x4 SB[4], SA[4];
#pragma unroll
            for (int t = 0; t < 4; ++t) {
                SB[t] = (f32x4){0.f, 0.f, 0.f, 0.f};
                SB[t] = mfma16(qB0, kf[t][0], SB[t]);
                SB[t] = mfma16(qB1, kf[t][1], SB[t]);
            }
            if (doA) {
#pragma unroll
                for (int t = 0; t < 4; ++t) {
                    SA[t] = (f32x4){0.f, 0.f, 0.f, 0.f};
                    SA[t] = mfma16(qA0, kf[t][0], SA[t]);
                    SA[t] = mfma16(qA1, kf[t][1], SA[t]);
                }
            }

            if (key0 + 63 > qwB) {
#pragma unroll
                for (int t = 0; t < 4; ++t)
#pragma unroll
                    for (int r = 0; r < 4; ++r)
                        if (key0 + t * 16 + lo > qwB + hi * 4 + r) SB[t][r] = -1e30f;
            }
            if (doA && key0 + 63 > qwA) {
#pragma unroll
                for (int t = 0; t < 4; ++t)
#pragma unroll
                    for (int r = 0; r < 4; ++r)
                        if (key0 + t * 16 + lo > qwA + hi * 4 + r) SA[t][r] = -1e30f;
            }

            bf16x4v pk;
#pragma unroll
            for (int t = 0; t < 4; ++t) {
#pragma unroll
                for (int r = 0; r < 4; ++r) {
                    float p = exp2f(SB[t][r]);
                    LB[r] += p;
                    pk[r] = (__bf16)p;
                }
                *(bf16x4v*)&PT[wv][1][t * 16 + lo][hi * 4] = pk;   // ds_write_b64
            }
            if (doA) {
#pragma unroll
                for (int t = 0; t < 4; ++t) {
#pragma unroll
                    for (int r = 0; r < 4; ++r) {
                        float p = exp2f(SA[t][r]);
                        LA[r] += p;
                        pk[r] = (__bf16)p;
                    }
                    *(bf16x4v*)&PT[wv][0][t * 16 + lo][hi * 4] = pk;
                }
            }
            asm volatile("s_waitcnt lgkmcnt(0)" ::: "memory");   // P^T stores visible

            bf16x4v b00, b01, b10, b11, a00, a01, a10, a11;
            TRRD(b00, ptB);          TRRD128(b01, ptB);
            TRRD(b10, ptB + 1024);   TRRD128(b11, ptB + 1024);
            if (doA) {
                TRRD(a00, ptA);        TRRD128(a01, ptA);
                TRRD(a10, ptA + 1024); TRRD128(a11, ptA + 1024);
            }
            asm volatile("s_waitcnt lgkmcnt(0)" ::: "memory");
            __builtin_amdgcn_sched_barrier(0);                   // rule #18

            const bf16x8 paB0 = __builtin_shufflevector(b00, b01, 0, 1, 2, 3, 4, 5, 6, 7);
            const bf16x8 paB1 = __builtin_shufflevector(b10, b11, 0, 1, 2, 3, 4, 5, 6, 7);
#pragma unroll
            for (int t = 0; t < 4; ++t) {
                OB[t] = mfma16(paB0, vf[t][0], OB[t]);
                OB[t] = mfma16(paB1, vf[t][1], OB[t]);
            }
            if (doA) {
                const bf16x8 paA0 = __builtin_shufflevector(a00, a01, 0, 1, 2, 3, 4, 5, 6, 7);
                const bf16x8 paA1 = __builtin_shufflevector(a10, a11, 0, 1, 2, 3, 4, 5, 6, 7);
#pragma unroll
                for (int t = 0; t < 4; ++t) {
                    OA[t] = mfma16(paA0, vf[t][0], OA[t]);
                    OA[t] = mfma16(paA1, vf[t][1], OA[t]);
                }
            }
        }
    }

    const int b = bh >> 3, h = bh & 7;
#pragma unroll
    for (int c = 0; c < 2; ++c) {
        const int qw = c ? qwB : qwA;
        f32x4* O = c ? OB : OA;
        float* Lp = c ? LB : LA;
        float rL[4];
#pragma unroll
        for (int r = 0; r < 4; ++r) {
            float Ls = Lp[r];
#pragma unroll
            for (int off = 1; off < 16; off <<= 1)
                Ls += __shfl_xor(Ls, off, 64);
            rL[r] = 1.f / Ls;
        }
#pragma unroll
        for (int t = 0; t < 4; ++t)
#pragma unroll
            for (int r = 0; r < 4; ++r) {
                int q = qw + hi * 4 + r;
                ao[((size_t)b * N_ + q) * C_ + h * HD_ + t * 16 + lo] =
                    __float2bfloat16(O[t][r] * rL[r]);
            }
    }
}

// ---------------- Projection GEMM: 512x8192x512, 64j x 128n tiles, ping-pong dbuf ----------------
__global__ __launch_bounds__(256) void proj_mfma(const bf16* __restrict__ aob,
                                                 const bf16* __restrict__ Wpb,
                                                 const float* __restrict__ bp,
                                                 float* __restrict__ out) {
    __shared__ bf16 As[2][64 * 32];
    __shared__ bf16 Bs[2][128 * 32];
    const int tid = threadIdx.x, w = tid >> 6, lane = tid & 63;
    const int lo = lane & 15, hi = lane >> 4;
    const int j0 = blockIdx.x * 64;
    const int n0 = blockIdx.y * 128;
    const int b  = n0 >> 10;

    const int r4 = lane >> 2;
    const int ss = (r4 & 3) ^ ((r4 >> 2) & 3);           // == s(srow) for both A (w*16+r4) and B (w*32+r4)
    const int c8 = ((lane & 3) ^ ss) * 8;                // pre-swizzled global chunk
    const int sl = (lane & 3) ^ ((lane >> 2) & 3);       // read swizzle s(lo)
    const bf16* gA = Wpb + (size_t)(j0 + w * 16 + r4) * C_ + c8;
    const bf16* gB = aob + (size_t)(n0 + w * 32 + r4) * C_ + c8;
    const int lwsA = (w * 16) * 32;
    const int lwsB = (w * 32) * 32;

    f32x4 acc[2][4];
#pragma unroll
    for (int mt = 0; mt < 2; ++mt)
#pragma unroll
        for (int jt = 0; jt < 4; ++jt)
            acc[mt][jt] = (f32x4){0.f, 0.f, 0.f, 0.f};

    auto STAGE = [&](bf16* Ab, bf16* Bb, int k0) {
        ld_lds16(gA + k0, Ab + lwsA);
        ld_lds16(gB + k0, Bb + lwsB);
        ld_lds16(gB + (size_t)16 * C_ + k0, Bb + lwsB + 16 * 32);
    };
    auto COMPUTE = [&](const bf16* Ab, const bf16* Bb) {
        bf16x8 af[2], bfr[4];
#pragma unroll
        for (int mt = 0; mt < 2; ++mt)
            af[mt] = *(const bf16x8*)(Ab + ((w & 1) * 32 + mt * 16 + lo) * 32 + (hi ^ sl) * 8);
#pragma unroll
        for (int jt = 0; jt < 4; ++jt)
            bfr[jt] = *(const bf16x8*)(Bb + ((w >> 1) * 64 + jt * 16 + lo) * 32 + (hi ^ sl) * 8);
#pragma unroll
        for (int mt = 0; mt < 2; ++mt)
#pragma unroll
            for (int jt = 0; jt < 4; ++jt)
                acc[mt][jt] = mfma16(af[mt], bfr[jt], acc[mt][jt]);
    };

    STAGE(As[0], Bs[0], 0);
#pragma unroll
    for (int k0 = 0; k0 < C_; k0 += 64) {
        __syncthreads();
        if (k0 + 32 < C_) STAGE(As[1], Bs[1], k0 + 32);
        COMPUTE(As[0], Bs[0]);
        __syncthreads();
        if (k0 + 64 < C_) STAGE(As[0], Bs[0], k0 + 64);
        COMPUTE(As[1], Bs[1]);
    }

#pragma unroll
    for (int mt = 0; mt < 2; ++mt)
#pragma unroll
        for (int r = 0; r < 4; ++r) {
            const int j = j0 + (w & 1) * 32 + mt * 16 + hi * 4 + r;
            const float bias = bp[j];
            float* op = out + ((size_t)(b * C_ + j)) * N_ + (n0 & 1023) + (w >> 1) * 64 + lo;
#pragma unroll
            for (int jt = 0; jt < 4; ++jt)
                op[jt * 16] = acc[mt][jt][r] + bias;
        }
}

extern "C" void kernel_launch(void* const* d_in, const int* in_sizes, int n_in,
                              void* d_out, int out_size, void* d_ws, size_t ws_size,
                              hipStream_t stream) {
    const float* x  = (const float*)d_in[0];
    const float* Wq = (const float*)d_in[1];
    const float* bq = (const float*)d_in[2];
    const float* Wp = (const float*)d_in[3];
    const float* bp = (const float*)d_in[4];
    float* out = (float*)d_out;

    const size_t headElems = (size_t)B_ * NH_ * N_ * HD_;
    bf16* xb  = (bf16*)d_ws;
    bf16* Wqb = xb + (size_t)B_ * N_ * C_;
    bf16* Wpb = Wqb + (size_t)C3_ * C_;
    bf16* Qb  = Wpb + (size_t)C_ * C_;
    bf16* Kb  = Qb + headElems;
    bf16* Vt  = Kb + headElems;
    bf16* aob = Vt + headElems;

    prep<<<dim3(4096 + 1024), dim3(256), 0, stream>>>(x, Wq, Wp, xb, Wqb, Wpb);

    qkv_mfma<<<dim3(C3_ / 128, (B_ * N_) / 128), dim3(256), 0, stream>>>(xb, Wqb, bq, Qb, Kb, Vt);
    attn_mfma<<<dim3(8 * 64), dim3(256), 0, stream>>>(Qb, Kb, Vt, aob);
    proj_mfma<<<dim3(C_ / 64, (B_ * N_) / 128), dim3(256), 0, stream>>>(aob, Wpb, bp, out);
}